// Round 1
// baseline (13026.910 us; speedup 1.0000x reference)
//
#include <hip/hip_runtime.h>
#include <math.h>

#define BB   64
#define TT   256
#define DIN  512
#define HH   1024

// fast sigmoid / tanh via hardware exp
__device__ __forceinline__ float sig_(float x) { return 1.f / (1.f + __expf(-x)); }
__device__ __forceinline__ float th_(float x)  { return 2.f / (1.f + __expf(-2.f * x)) - 1.f; }

// MAC over one 256-k chunk: act from LDS (xor-swizzled), 4 gate-weight rows (uniform -> s_load)
__device__ __forceinline__ void mac_chunk(
    const float4* __restrict__ lds, int lane,
    const float* __restrict__ w0, const float* __restrict__ w1,
    const float* __restrict__ w2, const float* __restrict__ w3,
    float& acc0, float& acc1, float& acc2, float& acc3)
{
#pragma unroll 4
    for (int g4 = 0; g4 < 64; ++g4) {
        float4 a  = lds[lane * 64 + (g4 ^ lane)];
        float4 u0 = *(const float4*)(w0 + g4 * 4);
        float4 u1 = *(const float4*)(w1 + g4 * 4);
        float4 u2 = *(const float4*)(w2 + g4 * 4);
        float4 u3 = *(const float4*)(w3 + g4 * 4);
        acc0 = fmaf(a.w, u0.w, fmaf(a.z, u0.z, fmaf(a.y, u0.y, fmaf(a.x, u0.x, acc0))));
        acc1 = fmaf(a.w, u1.w, fmaf(a.z, u1.z, fmaf(a.y, u1.y, fmaf(a.x, u1.x, acc1))));
        acc2 = fmaf(a.w, u2.w, fmaf(a.z, u2.z, fmaf(a.y, u2.y, fmaf(a.x, u2.x, acc2))));
        acc3 = fmaf(a.w, u3.w, fmaf(a.z, u3.z, fmaf(a.y, u3.y, fmaf(a.x, u3.x, acc3))));
    }
}

// One LSTM timestep.
// grid = 256 blocks x 256 threads. Block owns h-columns [blk*4, blk*4+4), one wave per
// column, lane = batch row b (B==64==wave size).
// act = [x_t | h_{t-1}] (K=1536) staged in LDS chunks of 256 k, layout [b][k] with
// granule xor-swizzle (g^b) -> conflict-minimal ds_write_b128 / ds_read_b128.
// h_{t-1} is read straight out of d_out[:, t-1, :]; c state lives transposed in ws.
__global__ __launch_bounds__(256) void lstm_step(
    const float* __restrict__ x,   const float* __restrict__ wih,
    const float* __restrict__ whh, const float* __restrict__ bih,
    const float* __restrict__ bhh, float* __restrict__ out,
    float* __restrict__ cT, int t)
{
    __shared__ float4 lds[64 * 64];   // 64 KiB: 64 rows(b) x 64 granules(float4)

    const int tid  = threadIdx.x;
    const int lane = tid & 63;
    const int wv   = tid >> 6;
    const int j    = __builtin_amdgcn_readfirstlane((int)(blockIdx.x * 4 + wv)); // h column

    float acc0 = bih[0 * HH + j] + bhh[0 * HH + j];
    float acc1 = bih[1 * HH + j] + bhh[1 * HH + j];
    float acc2 = bih[2 * HH + j] + bhh[2 * HH + j];
    float acc3 = bih[3 * HH + j] + bhh[3 * HH + j];

    // ---- x chunks: k0 = 0, 256 ----
    for (int c = 0; c < 2; ++c) {
        const int k0 = c * 256;
#pragma unroll
        for (int i = 0; i < 16; ++i) {
            int idx = i * 256 + tid;      // 0..4095
            int row = idx >> 6;           // b
            int g   = idx & 63;           // k-granule
            float4 v = *(const float4*)(x + (size_t)row * (TT * DIN) + (size_t)t * DIN + k0 + g * 4);
            lds[row * 64 + (g ^ row)] = v;
        }
        __syncthreads();
        const float* w0 = wih + (size_t)(0 * HH + j) * DIN + k0;
        const float* w1 = wih + (size_t)(1 * HH + j) * DIN + k0;
        const float* w2 = wih + (size_t)(2 * HH + j) * DIN + k0;
        const float* w3 = wih + (size_t)(3 * HH + j) * DIN + k0;
        mac_chunk(lds, lane, w0, w1, w2, w3, acc0, acc1, acc2, acc3);
        __syncthreads();
    }

    // ---- h chunks: kh0 = 0, 256, 512, 768 ----
    for (int c = 0; c < 4; ++c) {
        const int kh0 = c * 256;
        if (t == 0) {
#pragma unroll
            for (int i = 0; i < 16; ++i) {
                int idx = i * 256 + tid;
                int row = idx >> 6;
                int g   = idx & 63;
                lds[row * 64 + (g ^ row)] = make_float4(0.f, 0.f, 0.f, 0.f);
            }
        } else {
#pragma unroll
            for (int i = 0; i < 16; ++i) {
                int idx = i * 256 + tid;
                int row = idx >> 6;
                int g   = idx & 63;
                float4 v = *(const float4*)(out + (size_t)row * (TT * HH) + (size_t)(t - 1) * HH + kh0 + g * 4);
                lds[row * 64 + (g ^ row)] = v;
            }
        }
        __syncthreads();
        const float* w0 = whh + (size_t)(0 * HH + j) * HH + kh0;
        const float* w1 = whh + (size_t)(1 * HH + j) * HH + kh0;
        const float* w2 = whh + (size_t)(2 * HH + j) * HH + kh0;
        const float* w3 = whh + (size_t)(3 * HH + j) * HH + kh0;
        mac_chunk(lds, lane, w0, w1, w2, w3, acc0, acc1, acc2, acc3);
        __syncthreads();
    }

    // ---- pointwise gates + state update ----
    float gi = sig_(acc0);
    float gf = sig_(acc1);
    float gg = th_(acc2);
    float go = sig_(acc3);
    float cprev = (t == 0) ? 0.f : cT[j * 64 + lane];
    float cn = fmaf(gf, cprev, gi * gg);
    cT[j * 64 + lane] = cn;                                       // coalesced per wave
    out[(size_t)lane * (TT * HH) + (size_t)t * HH + j] = go * th_(cn); // scattered 4B (accepted, round 1)
}

extern "C" void kernel_launch(void* const* d_in, const int* in_sizes, int n_in,
                              void* d_out, int out_size, void* d_ws, size_t ws_size,
                              hipStream_t stream)
{
    const float* x   = (const float*)d_in[0];
    const float* wih = (const float*)d_in[1];
    const float* whh = (const float*)d_in[2];
    const float* bih = (const float*)d_in[3];
    const float* bhh = (const float*)d_in[4];
    float* out = (float*)d_out;
    float* cT  = (float*)d_ws;   // 1024 x 64 f32 = 256 KiB, well under any ws_size

    for (int t = 0; t < TT; ++t) {
        lstm_step<<<dim3(256), dim3(256), 0, stream>>>(x, wih, whh, bih, bhh, out, cT, t);
    }
}

// Round 8
// 3293.667 us; speedup vs baseline: 3.9551x; 3.9551x over previous
//
#include <hip/hip_runtime.h>
#include <math.h>

#define BB   64
#define TT   256
#define DIN  512
#define HH   1024
#define KF   1536   // fused K = DIN + HH
#define NG   4096   // 4*HH gate columns

typedef short  bf16x8 __attribute__((ext_vector_type(8)));
typedef float  f32x4  __attribute__((ext_vector_type(4)));

// ---- ws layout (bytes) ----
// Wf   : bf16 [4096][1536]            12,582,912
// xb   : bf16 [256 t][64 b][512 k]    16,777,216
// hb   : bf16 [256 jblk][64 b][4 jo]     131,072
// cT   : f32  [1024 j][64 b]             262,144
#define WF_OFF 0
#define XB_OFF (12582912)
#define HB_OFF (XB_OFF + 16777216)
#define CT_OFF (HB_OFF + 131072)

// precise activations: pointwise phase is ~0.3% of step cost, spend it on accuracy
__device__ __forceinline__ float sig_(float x) { return 1.f / (1.f + expf(-x)); }
__device__ __forceinline__ float th_(float x)  { return tanhf(x); }

__device__ __forceinline__ unsigned short f2b(float f) {
    union { float f; unsigned u; } v; v.f = f;
    unsigned r = (v.u + 0x7FFF + ((v.u >> 16) & 1)) >> 16;   // RNE
    return (unsigned short)r;
}

// ---- convert weights: Wf[n][k] = bf16( k<512 ? wih[n][k] : whh[n][k-512] ) ----
__global__ __launch_bounds__(256) void conv_w(
    const float* __restrict__ wih, const float* __restrict__ whh,
    unsigned short* __restrict__ Wf)
{
    int gid = blockIdx.x * 256 + threadIdx.x;      // 786432 granules of 8
    int n   = gid / 192;
    int kg  = gid - n * 192;
    const float* src = (kg < 64) ? (wih + (size_t)n * DIN + kg * 8)
                                 : (whh + (size_t)n * HH + (kg - 64) * 8);
    float4 a = *(const float4*)(src);
    float4 b = *(const float4*)(src + 4);
    unsigned short o[8] = { f2b(a.x), f2b(a.y), f2b(a.z), f2b(a.w),
                            f2b(b.x), f2b(b.y), f2b(b.z), f2b(b.w) };
    *(uint4*)(Wf + (size_t)n * KF + kg * 8) = *(const uint4*)o;
}

// ---- convert x: xb[t][b][k] = bf16(x[b][t][k]) ----
__global__ __launch_bounds__(256) void conv_x(
    const float* __restrict__ x, unsigned short* __restrict__ xb)
{
    int gid = blockIdx.x * 256 + threadIdx.x;      // 1,048,576 granules of 8
    int t   = gid >> 12;                           // / (64*64)
    int rem = gid & 4095;
    int b   = rem >> 6;
    int kg  = rem & 63;
    const float* src = x + (size_t)b * (TT * DIN) + (size_t)t * DIN + kg * 8;
    float4 a = *(const float4*)(src);
    float4 c = *(const float4*)(src + 4);
    unsigned short o[8] = { f2b(a.x), f2b(a.y), f2b(a.z), f2b(a.w),
                            f2b(c.x), f2b(c.y), f2b(c.z), f2b(c.w) };
    *(uint4*)(xb + (size_t)t * (BB * DIN) + (size_t)b * DIN + kg * 8) = *(const uint4*)o;
}

// ---- one LSTM timestep, MFMA ----
// grid 256 x 256. Block owns h-cols [4*blk, 4*blk+4) => 16 gate cols (4 gates x 4 cols).
// Wave wv = M-tile (batches 16*wv..16*wv+15), N=16, K=1536 -> 48 mfma_f32_16x16x32_bf16.
// A (act) read straight from global: xb (x part) + hb (h part). B read straight from Wf.
// No barriers in main loop; 1KB/wave LDS scratch only for the epilogue transpose.
__global__ __launch_bounds__(256) void lstm_step(
    const unsigned short* __restrict__ Wf, const unsigned short* __restrict__ xb,
    unsigned short* __restrict__ hb, float* __restrict__ cT,
    const float* __restrict__ bih, const float* __restrict__ bhh,
    float* __restrict__ out, int t)
{
    __shared__ float scr[4][16][17];   // [wave][m][c], +1 pad

    const int tid  = threadIdx.x;
    const int lane = tid & 63;
    const int wv   = tid >> 6;
    const int lo   = lane & 15;        // A row (m) / B col (c) selector
    const int hi   = lane >> 4;        // k-group selector

    // B column map: c=lo -> gate gq = lo>>2, col offset jo = lo&3
    const int gq = lo >> 2;
    const int jo = lo & 3;
    const int j0 = blockIdx.x * 4;
    const int n  = gq * HH + j0 + jo;
    const unsigned short* wrow = Wf + (size_t)n * KF;

    const int b = 16 * wv + lo;        // this lane's A batch row

    const float bias = bih[n] + bhh[n];
    f32x4 acc = { bias, bias, bias, bias };

    // ---- x part: K = 0..512 ----
    const unsigned short* xrow = xb + (size_t)t * (BB * DIN) + (size_t)b * DIN;
#pragma unroll
    for (int kk = 0; kk < 16; ++kk) {
        const int k = kk * 32 + hi * 8;
        bf16x8 af = *(const bf16x8*)(xrow + k);
        bf16x8 bf = *(const bf16x8*)(wrow + k);
        acc = __builtin_amdgcn_mfma_f32_16x16x32_bf16(af, bf, acc, 0, 0, 0);
    }

    // ---- h part: K = 512..1536 (skip at t==0: h == 0) ----
    if (t > 0) {
#pragma unroll
        for (int kk = 0; kk < 32; ++kk) {
            const int jb = kk * 8 + hi * 2;                   // first jblk of this frag
            const unsigned short* hp = hb + (size_t)jb * 256 + b * 4;
            uint2 v0 = *(const uint2*)(hp);
            uint2 v1 = *(const uint2*)(hp + 256);
            union { uint4 u; bf16x8 f; } uu;
            uu.u.x = v0.x; uu.u.y = v0.y; uu.u.z = v1.x; uu.u.w = v1.y;
            bf16x8 bf = *(const bf16x8*)(wrow + 512 + kk * 32 + hi * 8);
            acc = __builtin_amdgcn_mfma_f32_16x16x32_bf16(uu.f, bf, acc, 0, 0, 0);
        }
    }

    // ---- epilogue: transpose via LDS, pointwise, state update ----
#pragma unroll
    for (int r = 0; r < 4; ++r)
        scr[wv][4 * hi + r][lo] = acc[r];
    __syncthreads();

    // lane l: m = lo (batch 16*wv+lo), j-offset = hi
    const int bidx = 16 * wv + lo;
    const int jj   = j0 + hi;
    float vi = scr[wv][lo][ 0 + hi];
    float vf = scr[wv][lo][ 4 + hi];
    float vg = scr[wv][lo][ 8 + hi];
    float vo = scr[wv][lo][12 + hi];

    float i_t = sig_(vi);
    float f_t = sig_(vf);
    float g_t = th_(vg);
    float o_t = sig_(vo);
    float cprev = (t > 0) ? cT[jj * 64 + bidx] : 0.f;
    float cn = fmaf(f_t, cprev, i_t * g_t);
    cT[jj * 64 + bidx] = cn;
    float hn = o_t * th_(cn);

    out[(size_t)bidx * (TT * HH) + (size_t)t * HH + jj] = hn;
    // hb[jblk=blockIdx][b][jo=hi]
    hb[(size_t)blockIdx.x * 256 + bidx * 4 + hi] = f2b(hn);
}

extern "C" void kernel_launch(void* const* d_in, const int* in_sizes, int n_in,
                              void* d_out, int out_size, void* d_ws, size_t ws_size,
                              hipStream_t stream)
{
    const float* x   = (const float*)d_in[0];
    const float* wih = (const float*)d_in[1];
    const float* whh = (const float*)d_in[2];
    const float* bih = (const float*)d_in[3];
    const float* bhh = (const float*)d_in[4];
    float* out = (float*)d_out;

    char* ws = (char*)d_ws;
    unsigned short* Wf = (unsigned short*)(ws + WF_OFF);
    unsigned short* xb = (unsigned short*)(ws + XB_OFF);
    unsigned short* hb = (unsigned short*)(ws + HB_OFF);
    float*          cT = (float*)(ws + CT_OFF);

    conv_w<<<dim3(3072), dim3(256), 0, stream>>>(wih, whh, Wf);
    conv_x<<<dim3(4096), dim3(256), 0, stream>>>(x, xb);

    for (int t = 0; t < TT; ++t) {
        lstm_step<<<dim3(256), dim3(256), 0, stream>>>(Wf, xb, hb, cT, bih, bhh, out, t);
    }
}